// Round 1
// baseline (13.131 us; speedup 1.0000x reference)
//
#include <hip/hip_runtime.h>
#include <hip/hip_bf16.h>

// Problem: triplane aggregation.
//   C=32, R=128.
//   p_yz[y][z] = sum_c yz_feat[c][y][z] * W[c]
//   p_xz[x][z] = sum_c xz_feat[c][x][z] * W[C+c]
//   p_xy[x][y] = sum_c xy_feat[c][x][y] * W[2C+c]
//   out[x][y][z] = sigmoid(p_yz[y][z] + p_xz[x][z] + p_xy[x][y] + b)
// out shape (1,1,128,128,128) float32, flat index = x*16384 + y*128 + z.

#define C 32
#define R 128
#define PLANE (R * R)   // 16384

__global__ void triplane_proj_kernel(const float* __restrict__ yz,
                                     const float* __restrict__ xz,
                                     const float* __restrict__ xy,
                                     const float* __restrict__ W,
                                     float* __restrict__ p) {
    int i = blockIdx.x * blockDim.x + threadIdx.x;   // 0 .. 3*PLANE-1
    if (i >= 3 * PLANE) return;
    int plane = i >> 14;        // 0: yz, 1: xz, 2: xy
    int sp    = i & (PLANE - 1);
    const float* src = (plane == 0) ? yz : ((plane == 1) ? xz : xy);
    const float* w   = W + plane * C;
    float acc = 0.0f;
#pragma unroll
    for (int c = 0; c < C; ++c) {
        acc += src[c * PLANE + sp] * w[c];
    }
    p[i] = acc;   // layout: p_yz at [0], p_xz at [PLANE], p_xy at [2*PLANE]
}

__global__ void triplane_out_kernel(const float* __restrict__ p,
                                    const float* __restrict__ b,
                                    float* __restrict__ out) {
    // one thread -> 4 consecutive z values (float4)
    int t = blockIdx.x * blockDim.x + threadIdx.x;   // 0 .. 128^3/4 - 1
    int z4 = t & 31;            // 32 float4 groups per z-row
    int y  = (t >> 5) & 127;
    int x  = t >> 12;

    float pxy = p[2 * PLANE + x * R + y];
    float4 pyz = *reinterpret_cast<const float4*>(p + y * R + z4 * 4);
    float4 pxz = *reinterpret_cast<const float4*>(p + PLANE + x * R + z4 * 4);
    float base = pxy + b[0];

    float4 r;
    float l0 = pyz.x + pxz.x + base;
    float l1 = pyz.y + pxz.y + base;
    float l2 = pyz.z + pxz.z + base;
    float l3 = pyz.w + pxz.w + base;
    r.x = 1.0f / (1.0f + __expf(-l0));
    r.y = 1.0f / (1.0f + __expf(-l1));
    r.z = 1.0f / (1.0f + __expf(-l2));
    r.w = 1.0f / (1.0f + __expf(-l3));

    reinterpret_cast<float4*>(out)[t] = r;
}

extern "C" void kernel_launch(void* const* d_in, const int* in_sizes, int n_in,
                              void* d_out, int out_size, void* d_ws, size_t ws_size,
                              hipStream_t stream) {
    const float* yz = (const float*)d_in[0];
    const float* xz = (const float*)d_in[1];
    const float* xy = (const float*)d_in[2];
    const float* W  = (const float*)d_in[3];
    const float* b  = (const float*)d_in[4];
    float* out = (float*)d_out;
    float* p   = (float*)d_ws;   // 3*PLANE floats = 192 KB scratch

    {
        int total = 3 * PLANE;           // 49152
        int block = 256;
        int grid  = (total + block - 1) / block;   // 192
        triplane_proj_kernel<<<grid, block, 0, stream>>>(yz, xz, xy, W, p);
    }
    {
        int total4 = (R * R * R) / 4;    // 524288
        int block = 256;
        int grid  = total4 / block;      // 2048
        triplane_out_kernel<<<grid, block, 0, stream>>>(p, b, out);
    }
}

// Round 2
// 12.707 us; speedup vs baseline: 1.0334x; 1.0334x over previous
//
#include <hip/hip_runtime.h>
#include <hip/hip_bf16.h>

// Triplane aggregation, fully fused single kernel.
//   C=32, R=128.
//   p_yz[y][z] = sum_c yz_feat[c][y][z] * W[c]
//   p_xz[x][z] = sum_c xz_feat[c][x][z] * W[C+c]
//   p_xy[x][y] = sum_c xy_feat[c][x][y] * W[2C+c]
//   out[x][y][z] = sigmoid(p_yz[y][z] + p_xz[x][z] + p_xy[x][y] + b)
// out flat index = x*16384 + y*128 + z (float32).
//
// Fusion strategy: each block owns an 8(x) x 8(y) x 64(z) output tile and
// recomputes the projection slices it needs into LDS (128 KB of L2-resident
// feature reads per block; planes are 2 MB each so they live in L2/L3 after
// first touch). One launch instead of two -> saves a dispatch of overhead.

#define C 32
#define R 128
#define PLANE (R * R)   // 16384

#define BX 8
#define BY 8
#define BZ 64

__global__ __launch_bounds__(256) void triplane_fused_kernel(
        const float* __restrict__ yz,
        const float* __restrict__ xz,
        const float* __restrict__ xy,
        const float* __restrict__ W,
        const float* __restrict__ bptr,
        float* __restrict__ out) {
    __shared__ float pyz[BY][BZ];
    __shared__ float pxz[BX][BZ];
    __shared__ float pxy[BX][BY];
    __shared__ float w[3 * C];

    const int bid = blockIdx.x;           // 0..511
    const int zh = bid & 1;               // z half
    const int yt = (bid >> 1) & 15;       // y tile
    const int xt = bid >> 5;              // x tile
    const int x0 = xt * BX, y0 = yt * BY, z0 = zh * BZ;
    const int t = threadIdx.x;            // 0..255

    if (t < 3 * C) w[t] = W[t];
    __syncthreads();

    // p_yz tile: 8 y-rows x 64 z = 512 outputs, 2 per thread
    for (int e = t; e < BY * BZ; e += 256) {
        int yi = e >> 6, zi = e & 63;
        const float* src = yz + (y0 + yi) * R + z0 + zi;
        float acc = 0.0f;
#pragma unroll
        for (int c = 0; c < C; ++c) acc += src[c * PLANE] * w[c];
        pyz[yi][zi] = acc;
    }
    // p_xz tile
    for (int e = t; e < BX * BZ; e += 256) {
        int xi = e >> 6, zi = e & 63;
        const float* src = xz + (x0 + xi) * R + z0 + zi;
        float acc = 0.0f;
#pragma unroll
        for (int c = 0; c < C; ++c) acc += src[c * PLANE] * w[C + c];
        pxz[xi][zi] = acc;
    }
    // p_xy tile: 64 outputs, first wave only
    if (t < BX * BY) {
        int xi = t >> 3, yi = t & 7;
        const float* src = xy + (x0 + xi) * R + (y0 + yi);
        float acc = 0.0f;
#pragma unroll
        for (int c = 0; c < C; ++c) acc += src[c * PLANE] * w[2 * C + c];
        pxy[xi][yi] = acc;
    }
    const float bb = bptr[0];
    __syncthreads();

    // Output: 8x8 rows x 64 z = 1024 float4 stores, 4 per thread.
    const int z16 = t & 15;       // which float4 within the 64-z span
    const int r0 = t >> 4;        // 0..15
#pragma unroll
    for (int it = 0; it < 4; ++it) {
        int r = r0 + 16 * it;     // 0..63 -> (xi, yi)
        int xi = r >> 3, yi = r & 7;
        float base = pxy[xi][yi] + bb;
        float4 a = *reinterpret_cast<const float4*>(&pyz[yi][z16 * 4]);
        float4 c4 = *reinterpret_cast<const float4*>(&pxz[xi][z16 * 4]);
        float4 o;
        o.x = 1.0f / (1.0f + __expf(-(a.x + c4.x + base)));
        o.y = 1.0f / (1.0f + __expf(-(a.y + c4.y + base)));
        o.z = 1.0f / (1.0f + __expf(-(a.z + c4.z + base)));
        o.w = 1.0f / (1.0f + __expf(-(a.w + c4.w + base)));
        *reinterpret_cast<float4*>(out + (x0 + xi) * PLANE + (y0 + yi) * R + z0 + z16 * 4) = o;
    }
}

extern "C" void kernel_launch(void* const* d_in, const int* in_sizes, int n_in,
                              void* d_out, int out_size, void* d_ws, size_t ws_size,
                              hipStream_t stream) {
    const float* yz = (const float*)d_in[0];
    const float* xz = (const float*)d_in[1];
    const float* xy = (const float*)d_in[2];
    const float* W  = (const float*)d_in[3];
    const float* b  = (const float*)d_in[4];
    float* out = (float*)d_out;

    // grid: 16 x-tiles * 16 y-tiles * 2 z-halves = 512 blocks
    triplane_fused_kernel<<<512, 256, 0, stream>>>(yz, xz, xy, W, b, out);
}

// Round 4
// 10.411 us; speedup vs baseline: 1.2612x; 1.2205x over previous
//
#include <hip/hip_runtime.h>
#include <hip/hip_bf16.h>

// Triplane aggregation, fused single kernel, 16x16x16 tiles.
//   C=32, R=128.
//   p_yz[y][z] = sum_c yz_feat[c][y][z] * W[c]
//   p_xz[x][z] = sum_c xz_feat[c][x][z] * W[C+c]
//   p_xy[x][y] = sum_c xy_feat[c][x][y] * W[2C+c]
//   out[x][y][z] = sigmoid(p_yz[y][z] + p_xz[x][z] + p_xy[x][y] + b)
// out flat index = x*16384 + y*128 + z (float32).
//
// Tile shape rationale: per-block projection read volume is
//   128^3 * C * 4B * (1/BX + 1/BY + 1/BZ)  summed over the grid.
// 16x16x16 minimizes the sum (0.1875) vs 8x8x64 (0.2656): 50 MB vs 71 MB
// of L2/L3-resident reads. Grid stays 512 blocks (2/CU).

#define C 32
#define R 128
#define PLANE (R * R)   // 16384

#define BT 16           // tile edge (x, y, z all 16)

typedef float f32x4 __attribute__((ext_vector_type(4)));

__global__ __launch_bounds__(256) void triplane_fused_kernel(
        const float* __restrict__ yz,
        const float* __restrict__ xz,
        const float* __restrict__ xy,
        const float* __restrict__ W,
        const float* __restrict__ bptr,
        float* __restrict__ out) {
    __shared__ float pyz[BT][BT];
    __shared__ float pxz[BT][BT];
    __shared__ float pxy[BT][BT];
    __shared__ float w[3 * C];

    const int bid = blockIdx.x;           // 0..511 = 8(xt) * 8(yt) * 8(zt)
    const int zt = bid & 7;
    const int yt = (bid >> 3) & 7;
    const int xt = bid >> 6;
    const int x0 = xt * BT, y0 = yt * BT, z0 = zt * BT;
    const int t = threadIdx.x;            // 0..255

    if (t < 3 * C) w[t] = W[t];
    __syncthreads();

    // Each thread computes exactly one element of each projection tile.
    const int i0 = t >> 4;    // 0..15
    const int i1 = t & 15;    // 0..15

    // p_yz[yi][zi]
    {
        const float* src = yz + (y0 + i0) * R + (z0 + i1);
        float acc = 0.0f;
#pragma unroll
        for (int c = 0; c < C; ++c) acc += src[c * PLANE] * w[c];
        pyz[i0][i1] = acc;
    }
    // p_xz[xi][zi]
    {
        const float* src = xz + (x0 + i0) * R + (z0 + i1);
        float acc = 0.0f;
#pragma unroll
        for (int c = 0; c < C; ++c) acc += src[c * PLANE] * w[C + c];
        pxz[i0][i1] = acc;
    }
    // p_xy[xi][yi]
    {
        const float* src = xy + (x0 + i0) * R + (y0 + i1);
        float acc = 0.0f;
#pragma unroll
        for (int c = 0; c < C; ++c) acc += src[c * PLANE] * w[2 * C + c];
        pxy[i0][i1] = acc;
    }
    const float bb = bptr[0];
    __syncthreads();

    // Output: 16x16 rows x 16 z = 1024 float4, 4 per thread.
    // thread -> (z4 = t&3, yi = (t>>2)&15, xi = t>>6), iterate xi += 4.
    const int z4 = t & 3;
    const int yi = (t >> 2) & 15;
    const int xi0 = t >> 6;               // 0..3
#pragma unroll
    for (int it = 0; it < 4; ++it) {
        int xi = xi0 + 4 * it;            // 0..15
        float base = pxy[xi][yi] + bb;
        f32x4 a = *reinterpret_cast<const f32x4*>(&pyz[yi][z4 * 4]);
        f32x4 c4 = *reinterpret_cast<const f32x4*>(&pxz[xi][z4 * 4]);
        f32x4 o;
        o.x = __builtin_amdgcn_rcpf(1.0f + __expf(-(a.x + c4.x + base)));
        o.y = __builtin_amdgcn_rcpf(1.0f + __expf(-(a.y + c4.y + base)));
        o.z = __builtin_amdgcn_rcpf(1.0f + __expf(-(a.z + c4.z + base)));
        o.w = __builtin_amdgcn_rcpf(1.0f + __expf(-(a.w + c4.w + base)));
        __builtin_nontemporal_store(o,
            reinterpret_cast<f32x4*>(out + (x0 + xi) * PLANE + (y0 + yi) * R + z0 + z4 * 4));
    }
}

extern "C" void kernel_launch(void* const* d_in, const int* in_sizes, int n_in,
                              void* d_out, int out_size, void* d_ws, size_t ws_size,
                              hipStream_t stream) {
    const float* yz = (const float*)d_in[0];
    const float* xz = (const float*)d_in[1];
    const float* xy = (const float*)d_in[2];
    const float* W  = (const float*)d_in[3];
    const float* b  = (const float*)d_in[4];
    float* out = (float*)d_out;

    triplane_fused_kernel<<<512, 256, 0, stream>>>(yz, xz, xy, W, b, out);
}

// Round 7
// 10.392 us; speedup vs baseline: 1.2636x; 1.0019x over previous
//
#include <hip/hip_runtime.h>
#include <hip/hip_bf16.h>

// Triplane aggregation, fused single kernel, 16x16x16 tiles, XCD-aware.
//   C=32, R=128.
//   p_yz[y][z] = sum_c yz_feat[c][y][z] * W[c]
//   p_xz[x][z] = sum_c xz_feat[c][x][z] * W[C+c]
//   p_xy[x][y] = sum_c xy_feat[c][x][y] * W[2C+c]
//   out[x][y][z] = sigmoid(p_yz[y][z] + p_xz[x][z] + p_xy[x][y] + b)
// out flat index = x*16384 + y*128 + z (float32).
//
// XCD mapping: blockIdx round-robins across 8 XCDs, so xt = bid & 7 pins
// each 16-wide x-slab to one XCD. Per-XCD unique read set = yz plane (2 MB)
// + xz slab (0.25 MB) + xy slab (0.25 MB) = 2.5 MB < 4 MB L2 -> redundant
// projection re-reads become L2 hits instead of L3. zt is the fastest inner
// coordinate so z-adjacent tiles (sharing output cachelines) stay on the
// same XCD, temporally adjacent.

#define C 32
#define R 128
#define PLANE (R * R)   // 16384

#define BT 16           // tile edge (x, y, z all 16)

typedef float f32x4 __attribute__((ext_vector_type(4)));

__global__ __launch_bounds__(256) void triplane_fused_kernel(
        const float* __restrict__ yz,
        const float* __restrict__ xz,
        const float* __restrict__ xy,
        const float* __restrict__ W,
        const float* __restrict__ bptr,
        float* __restrict__ out) {
    __shared__ float pyz[BT][BT];
    __shared__ float pxz[BT][BT];
    __shared__ float pxy[BT][BT];
    __shared__ float w[3 * C];

    const int bid = blockIdx.x;           // 0..511
    const int xt = bid & 7;               // XCD id under round-robin dispatch
    const int inner = bid >> 3;           // 0..63
    const int zt = inner & 7;             // fastest within XCD
    const int yt = inner >> 3;
    const int x0 = xt * BT, y0 = yt * BT, z0 = zt * BT;
    const int t = threadIdx.x;            // 0..255

    if (t < 3 * C) w[t] = W[t];
    __syncthreads();

    // Projection phase: wave 0 -> pyz, wave 1 -> pxz, wave 2 -> pxy,
    // wave 3 idle. Each lane computes one float4 (4 consecutive inner
    // coords) accumulated over C -> 32 float4 loads per lane.
    const int pl = t >> 6;    // plane / wave
    const int g  = t & 63;    // group within plane
    if (pl < 3) {
        const int r0 = g >> 2;     // row 0..15
        const int q4 = g & 3;      // float4 column 0..3
        const float* src;
        const float* wp = w + pl * C;
        if (pl == 0)      src = yz + (y0 + r0) * R + z0 + q4 * 4;
        else if (pl == 1) src = xz + (x0 + r0) * R + z0 + q4 * 4;
        else              src = xy + (x0 + r0) * R + y0 + q4 * 4;
        f32x4 acc = {0.0f, 0.0f, 0.0f, 0.0f};
#pragma unroll
        for (int c = 0; c < C; ++c) {
            f32x4 v = *reinterpret_cast<const f32x4*>(src + c * PLANE);
            float wc = wp[c];
            acc.x += v.x * wc; acc.y += v.y * wc;
            acc.z += v.z * wc; acc.w += v.w * wc;
        }
        float* dst = (pl == 0) ? &pyz[r0][q4 * 4]
                   : (pl == 1) ? &pxz[r0][q4 * 4]
                               : &pxy[r0][q4 * 4];
        *reinterpret_cast<f32x4*>(dst) = acc;
    }
    const float bb = bptr[0];
    __syncthreads();

    // Output: 16x16 rows x 16 z = 1024 float4, 4 per thread.
    const int z4 = t & 3;
    const int yi = (t >> 2) & 15;
    const int xi0 = t >> 6;               // 0..3
#pragma unroll
    for (int it = 0; it < 4; ++it) {
        int xi = xi0 + 4 * it;            // 0..15
        float base = pxy[xi][yi] + bb;
        f32x4 a = *reinterpret_cast<const f32x4*>(&pyz[yi][z4 * 4]);
        f32x4 c4 = *reinterpret_cast<const f32x4*>(&pxz[xi][z4 * 4]);
        f32x4 o;
        o.x = __builtin_amdgcn_rcpf(1.0f + __expf(-(a.x + c4.x + base)));
        o.y = __builtin_amdgcn_rcpf(1.0f + __expf(-(a.y + c4.y + base)));
        o.z = __builtin_amdgcn_rcpf(1.0f + __expf(-(a.z + c4.z + base)));
        o.w = __builtin_amdgcn_rcpf(1.0f + __expf(-(a.w + c4.w + base)));
        __builtin_nontemporal_store(o,
            reinterpret_cast<f32x4*>(out + (x0 + xi) * PLANE + (y0 + yi) * R + z0 + z4 * 4));
    }
}

extern "C" void kernel_launch(void* const* d_in, const int* in_sizes, int n_in,
                              void* d_out, int out_size, void* d_ws, size_t ws_size,
                              hipStream_t stream) {
    const float* yz = (const float*)d_in[0];
    const float* xz = (const float*)d_in[1];
    const float* xy = (const float*)d_in[2];
    const float* W  = (const float*)d_in[3];
    const float* b  = (const float*)d_in[4];
    float* out = (float*)d_out;

    triplane_fused_kernel<<<512, 256, 0, stream>>>(yz, xz, xy, W, b, out);
}